// Round 5
// baseline (173.299 us; speedup 1.0000x reference)
//
#include <hip/hip_runtime.h>
#include <math.h>

// R9: instruction-issue diet. adder_ds and back rewritten: 2 px/thread
// (float2 global loads), 4 oc/block, weights+bn read as float4 from LDS
// (ds_read_b128) per 4-channel chunk -> ~4x fewer LDS instrs, 2x fewer
// global instrs, 8 independent accumulators. final_kernel float4-ized.
// mid3x3/c1/minmax unchanged from R8 (which passed at 170.1us).
//   minmax(64) -> front(848) -> mid3x3(512) -> back(512) -> final(784)

#define HW 784      // 28*28
#define NB 4
#define STAGE 100

// ---------------- wave/block reduction helpers (wave64) --------------------
__device__ __forceinline__ float wredMax(float v){
  for (int o = 32; o > 0; o >>= 1) v = fmaxf(v, __shfl_down(v, o, 64));
  return v;
}
__device__ __forceinline__ float wredMin(float v){
  for (int o = 32; o > 0; o >>= 1) v = fminf(v, __shfl_down(v, o, 64));
  return v;
}
__device__ __forceinline__ double wredSumD(double v){
  for (int o = 32; o > 0; o >>= 1) v += __shfl_down(v, o, 64);
  return v;
}

// blockDim = 256 (4 waves)
__device__ float blockMin4(float v){
  __shared__ float shn[4];
  __syncthreads();
  v = wredMin(v);
  if ((threadIdx.x & 63) == 0) shn[threadIdx.x >> 6] = v;
  __syncthreads();
  return fminf(fminf(shn[0], shn[1]), fminf(shn[2], shn[3]));
}
__device__ float blockMax4(float v){
  __shared__ float shx[4];
  __syncthreads();
  v = wredMax(v);
  if ((threadIdx.x & 63) == 0) shx[threadIdx.x >> 6] = v;
  __syncthreads();
  return fmaxf(fmaxf(shx[0], shx[1]), fmaxf(shx[2], shx[3]));
}

// ---- per-block BN stats: 4 channels, single value per thread --------------
__device__ void stats4(float v0, float v1, float v2, float v3,
                       double* sumP, double* sqP, int oc0){
  __shared__ double sred[4][8];
  __syncthreads();
  const int w = threadIdx.x >> 6;
  float vv[4] = {v0, v1, v2, v3};
  #pragma unroll
  for (int i = 0; i < 4; i++){
    double d = (double)vv[i];
    double s = wredSumD(d);
    double q = wredSumD(d * d);
    if ((threadIdx.x & 63) == 0){ sred[w][i] = s; sred[w][4 + i] = q; }
  }
  __syncthreads();
  if (threadIdx.x < 8){
    double tot = sred[0][threadIdx.x] + sred[1][threadIdx.x]
               + sred[2][threadIdx.x] + sred[3][threadIdx.x];
    int i = threadIdx.x & 3;
    if (threadIdx.x < 4) atomicAdd(&sumP[oc0 + i], tot);
    else                 atomicAdd(&sqP[oc0 + i],  tot);
  }
}
// ---- per-block BN stats: 4 channels, precomputed (sum, sumsq) per thread --
__device__ void stats4p(const double* s, const double* q,
                        double* sumP, double* sqP, int oc0){
  __shared__ double sredp[4][8];
  __syncthreads();
  const int w = threadIdx.x >> 6;
  #pragma unroll
  for (int i = 0; i < 4; i++){
    double ss = wredSumD(s[i]);
    double qq = wredSumD(q[i]);
    if ((threadIdx.x & 63) == 0){ sredp[w][i] = ss; sredp[w][4 + i] = qq; }
  }
  __syncthreads();
  if (threadIdx.x < 8){
    double tot = sredp[0][threadIdx.x] + sredp[1][threadIdx.x]
               + sredp[2][threadIdx.x] + sredp[3][threadIdx.x];
    int i = threadIdx.x & 3;
    if (threadIdx.x < 4) atomicAdd(&sumP[oc0 + i], tot);
    else                 atomicAdd(&sqP[oc0 + i],  tot);
  }
}
__device__ void stats2(float v0, float v1, double* sumP, double* sqP, int oc0){
  __shared__ double sred2[4][4];
  __syncthreads();
  const int w = threadIdx.x >> 6;
  float vv[2] = {v0, v1};
  #pragma unroll
  for (int i = 0; i < 2; i++){
    double d = (double)vv[i];
    double s = wredSumD(d);
    double q = wredSumD(d * d);
    if ((threadIdx.x & 63) == 0){ sred2[w][i] = s; sred2[w][2 + i] = q; }
  }
  __syncthreads();
  if (threadIdx.x < 4){
    double tot = sred2[0][threadIdx.x] + sred2[1][threadIdx.x]
               + sred2[2][threadIdx.x] + sred2[3][threadIdx.x];
    int i = threadIdx.x & 1;
    if (threadIdx.x < 2) atomicAdd(&sumP[oc0 + i], tot);
    else                 atomicAdd(&sqP[oc0 + i],  tot);
  }
}

// ---- KL partial accumulation: 4 sums -> 4 double atomics (256 thr) --------
__device__ void klAccum(float se, float sel, float sef, float sq, double* dst){
  __shared__ double kls[4][4];
  __syncthreads();
  const int w = threadIdx.x >> 6;
  double a0 = wredSumD((double)se);
  double a1 = wredSumD((double)sel);
  double a2 = wredSumD((double)sef);
  double a3 = wredSumD((double)sq);
  if ((threadIdx.x & 63) == 0){
    kls[w][0] = a0; kls[w][1] = a1; kls[w][2] = a2; kls[w][3] = a3;
  }
  __syncthreads();
  if (threadIdx.x < 4){
    double tot = kls[0][threadIdx.x] + kls[1][threadIdx.x]
               + kls[2][threadIdx.x] + kls[3][threadIdx.x];
    atomicAdd(&dst[threadIdx.x], tot);
  }
}

// ---- bin reconstruction (reference op order; exact bin indices) -----------
__device__ __forceinline__ float reconv(float vv, float mn, float rng,
                                        const float* saff){
  float q = (vv - mn) / rng * 100.0f;
  int idx = (int)floorf(q);
  float nv = 0.0f;
  if (idx < STAGE){
    int ci = idx < 0 ? 0 : (idx > STAGE - 1 ? STAGE - 1 : idx);
    nv = vv * saff[ci];
  }
  return nv;
}

// ---- reduce 16 per-block minmax partials (race-free, no atomics) ----------
__device__ __forceinline__ void mmReduce(const float* mmbuf, int tens,
                                         float& mn, float& mx){
  mn = 3.402823466e38f; mx = -3.402823466e38f;
  #pragma unroll
  for (int k = 0; k < 16; k++){
    mn = fminf(mn, mmbuf[tens * 32 + k]);
    mx = fmaxf(mx, mmbuf[tens * 32 + 16 + k]);
  }
}

// --------------- K0: partial min/max of 4 weight tensors + zero stats ------
__global__ __launch_bounds__(256) void minmax_kernel(
    const float* w0, int n0, const float* w1, int n1,
    const float* w2, int n2, const float* w3, int n3,
    float* mmbuf, double* dstat)
{
  if (threadIdx.x < 21) dstat[blockIdx.x * 21 + threadIdx.x] = 0.0;
  const int tens = blockIdx.x >> 4, slot = blockIdx.x & 15;
  const float* w; int n;
  if      (tens == 0){ w = w0; n = n0; }
  else if (tens == 1){ w = w1; n = n1; }
  else if (tens == 2){ w = w2; n = n2; }
  else               { w = w3; n = n3; }
  float mn = 3.402823466e38f, mx = -3.402823466e38f;
  for (int i = slot * 256 + threadIdx.x; i < n; i += 4096){
    float v = w[i];
    mn = fminf(mn, v); mx = fmaxf(mx, v);
  }
  mn = blockMin4(mn); mx = blockMax4(mx);
  if (threadIdx.x == 0){
    mmbuf[tens * 32 + slot]      = mn;
    mmbuf[tens * 32 + 16 + slot] = mx;
  }
}

// --------------- K1: front — adder_ds(v) + (adder_c1+PEG) + riders ---------
// blocks [0,512): adder_ds, 4 oc, 2 px/thread (chunk of 392), float4 weights
// blocks [512,768): adder_c1+peg, 4 oc, 7-row tile -> padded raw T2b
// blocks [768,832): recon+write f_c2 row + KL partial (t2)
// blocks [832,848): recon f_c3 slice (1024) + KL partial (t3)
__global__ __launch_bounds__(256) void front_kernel(
    const float* __restrict__ x,
    const float* __restrict__ w_ds, const float* __restrict__ aff_ds,
    const float* __restrict__ lap_ds,
    const float* __restrict__ w_c1, const float* __restrict__ aff_c1,
    const float* __restrict__ lap_c1,
    const float* __restrict__ w_c2, const float* __restrict__ aff_c2,
    const float* __restrict__ lap_c2, float* __restrict__ f_c2,
    const float* __restrict__ w_c3, const float* __restrict__ aff_c3,
    const float* __restrict__ lap_c3,
    const float* __restrict__ peg_w, const float* __restrict__ mmbuf,
    float* __restrict__ A, float* __restrict__ T2b, double* __restrict__ dS)
{
  const int t = threadIdx.x;
  if (blockIdx.x < 512){
    // ---------------- adder_ds (vectorized) ----------------
    const int a = blockIdx.x;
    const int chunk = a & 1, og = (a >> 1) & 63, b = a >> 7;
    const int oc0 = og * 4;
    __shared__ float saff[STAGE];
    __shared__ __align__(16) float sw[512];
    if (t < STAGE) saff[t] = aff_ds[t];
    float mn, mx; mmReduce(mmbuf, 0, mn, mx);
    const float rng = mx - mn;
    __syncthreads();
    for (int k = t; k < 512; k += 256)
      sw[k] = reconv(w_ds[oc0 * 128 + k], mn, rng, saff);
    __syncthreads();

    const int px0 = chunk * 392 + 2 * t;
    float a0x=0,a0y=0,a1x=0,a1y=0,a2x=0,a2y=0,a3x=0,a3y=0;
    if (t < 196){
      const float* xp = x + (size_t)b * 128 * HW + px0;
      #pragma unroll 4
      for (int c4 = 0; c4 < 32; c4++){
        const float4 w0 = *(const float4*)&sw[      c4*4];
        const float4 w1 = *(const float4*)&sw[128 + c4*4];
        const float4 w2 = *(const float4*)&sw[256 + c4*4];
        const float4 w3 = *(const float4*)&sw[384 + c4*4];
        const float2 x0 = *(const float2*)(xp + (size_t)(c4*4+0)*HW);
        const float2 x1 = *(const float2*)(xp + (size_t)(c4*4+1)*HW);
        const float2 x2 = *(const float2*)(xp + (size_t)(c4*4+2)*HW);
        const float2 x3 = *(const float2*)(xp + (size_t)(c4*4+3)*HW);
        a0x += fabsf(x0.x-w0.x)+fabsf(x1.x-w0.y)+fabsf(x2.x-w0.z)+fabsf(x3.x-w0.w);
        a0y += fabsf(x0.y-w0.x)+fabsf(x1.y-w0.y)+fabsf(x2.y-w0.z)+fabsf(x3.y-w0.w);
        a1x += fabsf(x0.x-w1.x)+fabsf(x1.x-w1.y)+fabsf(x2.x-w1.z)+fabsf(x3.x-w1.w);
        a1y += fabsf(x0.y-w1.x)+fabsf(x1.y-w1.y)+fabsf(x2.y-w1.z)+fabsf(x3.y-w1.w);
        a2x += fabsf(x0.x-w2.x)+fabsf(x1.x-w2.y)+fabsf(x2.x-w2.z)+fabsf(x3.x-w2.w);
        a2y += fabsf(x0.y-w2.x)+fabsf(x1.y-w2.y)+fabsf(x2.y-w2.z)+fabsf(x3.y-w2.w);
        a3x += fabsf(x0.x-w3.x)+fabsf(x1.x-w3.y)+fabsf(x2.x-w3.z)+fabsf(x3.x-w3.w);
        a3y += fabsf(x0.y-w3.x)+fabsf(x1.y-w3.y)+fabsf(x2.y-w3.z)+fabsf(x3.y-w3.w);
      }
      float* op = A + ((size_t)(b * 256 + oc0)) * HW + px0;
      float2 r;
      r.x = -a0x; r.y = -a0y; *(float2*)(op         ) = r;
      r.x = -a1x; r.y = -a1y; *(float2*)(op +     HW) = r;
      r.x = -a2x; r.y = -a2y; *(float2*)(op + 2 * HW) = r;
      r.x = -a3x; r.y = -a3y; *(float2*)(op + 3 * HW) = r;
    }
    {
      double s[4], q[4];
      s[0] = -(double)a0x - (double)a0y;
      s[1] = -(double)a1x - (double)a1y;
      s[2] = -(double)a2x - (double)a2y;
      s[3] = -(double)a3x - (double)a3y;
      q[0] = (double)a0x*a0x + (double)a0y*a0y;
      q[1] = (double)a1x*a1x + (double)a1y*a1y;
      q[2] = (double)a2x*a2x + (double)a2y*a2y;
      q[3] = (double)a3x*a3x + (double)a3y*a3y;
      stats4p(s, q, dS + 0, dS + 256, oc0);
    }

    if (b == 0 && chunk == 0){     // KL partial for tensor 0 (own slice)
      float se = 0, sel = 0, sef = 0, sq = 0;
      for (int k = t; k < 512; k += 256){
        float l = lap_ds[oc0 * 128 + k];
        float e = expf(l);
        se += e; sel += e * l; sef += e * sw[k];
        sq += expf(sw[k]);
      }
      klAccum(se, sel, sef, sq, dS + 1280 + 0);
    }
  } else if (blockIdx.x < 768){
    // ---------------- adder_c1 + PEG -> padded raw T2b ----------------
    const int a = blockIdx.x - 512;
    const int rc = a & 3, og = (a >> 2) & 15, b = a >> 6;
    const int oc0 = og * 4;
    __shared__ float saffc[STAGE];
    __shared__ float swc[512];
    __shared__ float swp[36];
    __shared__ float sT1[4][256];
    if (t < STAGE) saffc[t] = aff_c1[t];
    if (t >= 128 && t < 164) swp[t - 128] = peg_w[oc0 * 9 + (t - 128)];
    float mn, mx; mmReduce(mmbuf, 1, mn, mx);
    const float rng = mx - mn;
    __syncthreads();
    for (int k = t; k < 512; k += 256)
      swc[k] = reconv(w_c1[oc0 * 128 + k], mn, rng, saffc);

    // border zeros for the rows this block owns (raw T2b must be 0 there)
    {
      float* tb = T2b + (size_t)(b * 64 + oc0) * 960;
      for (int i = t; i < 112; i += 256){
        int ch = i / 28;
        int j  = i - ch * 28;
        int r7 = j >> 2, cs = j & 3;
        int col = (cs == 0) ? 0 : 28 + cs;
        tb[(size_t)ch * 960 + (rc * 7 + 1 + r7) * 32 + col] = 0.0f;
      }
      if (rc == 0){               // full prow 0
        for (int i = t; i < 128; i += 256){
          int ch = i >> 5, col = i & 31;
          tb[(size_t)ch * 960 + col] = 0.0f;
        }
      }
      if (rc == 3){               // full prow 29
        for (int i = t; i < 128; i += 256){
          int ch = i >> 5, col = i & 31;
          tb[(size_t)ch * 960 + 29 * 32 + col] = 0.0f;
        }
      }
    }
    __syncthreads();

    if (t < 252){
      const int rr = t / 28;
      const int col = t - rr * 28;
      const int wr = rc * 7 - 1 + rr;
      float tv0 = 0, tv1 = 0, tv2 = 0, tv3 = 0;
      if (wr >= 0 && wr < 28){
        const float* xp = x + (size_t)b * 128 * HW + wr * 28 + col;
        float c0 = 0, c1 = 0, c2 = 0, c3 = 0;
        #pragma unroll 4
        for (int c = 0; c < 128; c++){
          float xv = xp[(size_t)c * HW];
          c0 += fabsf(xv - swc[c]);
          c1 += fabsf(xv - swc[128 + c]);
          c2 += fabsf(xv - swc[256 + c]);
          c3 += fabsf(xv - swc[384 + c]);
        }
        tv0 = -c0; tv1 = -c1; tv2 = -c2; tv3 = -c3;
      }
      sT1[0][t] = tv0; sT1[1][t] = tv1; sT1[2][t] = tv2; sT1[3][t] = tv3;
    }
    __syncthreads();
    float v0 = 0, v1 = 0, v2 = 0, v3 = 0;
    if (t < 196){
      const int r = t / 28, col = t - r * 28;
      float c0 = 0, c1 = 0, c2 = 0, c3 = 0;
      #pragma unroll
      for (int ky = 0; ky < 3; ky++){
        #pragma unroll
        for (int kx = 0; kx < 3; kx++){
          int cc = col + kx - 1;
          bool ok = (cc >= 0) && (cc < 28);
          int idx = ok ? ((r + ky) * 28 + cc) : 0;
          float p0 = ok ? sT1[0][idx] : 0.0f;
          float p1 = ok ? sT1[1][idx] : 0.0f;
          float p2 = ok ? sT1[2][idx] : 0.0f;
          float p3 = ok ? sT1[3][idx] : 0.0f;
          int wk = ky * 3 + kx;
          c0 += fabsf(p0 - swp[wk]);
          c1 += fabsf(p1 - swp[9 + wk]);
          c2 += fabsf(p2 - swp[18 + wk]);
          c3 += fabsf(p3 - swp[27 + wk]);
        }
      }
      v0 = -c0; v1 = -c1; v2 = -c2; v3 = -c3;
      const int prow = rc * 7 + r + 1;
      float* op = T2b + (size_t)(b * 64 + oc0) * 960 + prow * 32 + (col + 1);
      op[0] = v0; op[960] = v1; op[1920] = v2; op[2880] = v3;
    }
    stats4(v0, v1, v2, v3, dS + 512, dS + 576, oc0);

    if (b == 0 && rc == 0){        // KL partial for tensor 1
      float se = 0, sel = 0, sef = 0, sq = 0;
      for (int k = t; k < 512; k += 256){
        float l = lap_c1[oc0 * 128 + k];
        float e = expf(l);
        se += e; sel += e * l; sef += e * swc[k];
        sq += expf(swc[k]);
      }
      klAccum(se, sel, sef, sq, dS + 1280 + 4);
    }
  } else if (blockIdx.x < 832){
    // ---------------- f_c2 writer + KL (tensor 2) ----------------
    const int j = blockIdx.x - 768;          // oc row 0..63, 576 elems
    __shared__ float saff2[STAGE];
    if (t < STAGE) saff2[t] = aff_c2[t];
    float mn, mx; mmReduce(mmbuf, 2, mn, mx);
    const float rng = mx - mn;
    __syncthreads();
    float se = 0, sel = 0, sef = 0, sq = 0;
    for (int k = t; k < 576; k += 256){
      float nv = reconv(w_c2[j * 576 + k], mn, rng, saff2);
      f_c2[j * 576 + k] = nv;
      float l = lap_c2[j * 576 + k];
      float e = expf(l);
      se += e; sel += e * l; sef += e * nv; sq += expf(nv);
    }
    klAccum(se, sel, sef, sq, dS + 1280 + 8);
  } else {
    // ---------------- KL (tensor 3) ----------------
    const int j = blockIdx.x - 832;          // slice of 1024
    __shared__ float saff3[STAGE];
    if (t < STAGE) saff3[t] = aff_c3[t];
    float mn, mx; mmReduce(mmbuf, 3, mn, mx);
    const float rng = mx - mn;
    __syncthreads();
    float se = 0, sel = 0, sef = 0, sq = 0;
    for (int k = t; k < 1024; k += 256){
      float nv = reconv(w_c3[j * 1024 + k], mn, rng, saff3);
      float l = lap_c3[j * 1024 + k];
      float e = expf(l);
      se += e; sel += e * l; sef += e * nv; sq += expf(nv);
    }
    klAccum(se, sel, sef, sq, dS + 1280 + 12);
  }
}

// --------------- K2: adder 3x3; BN1 fused into float4 LDS staging ----------
__global__ __launch_bounds__(256) void mid3x3_kernel(
    const float* __restrict__ T2b, const float* __restrict__ f_c2,
    const float* __restrict__ g1, const float* __restrict__ b1,
    float* __restrict__ T3, double* __restrict__ dS)
{
  const int t = threadIdx.x;
  const int a = blockIdx.x;
  const int chunk = a & 3, og = (a >> 2) & 31, b = a >> 7;
  const int oc0 = og * 2;
  __shared__ float sT[64 * 288];           // [c][rr 0..8][cl 0..31]
  __shared__ float ssc[64], ssb[64];

  if (t < 64){
    double s  = dS[512 + t] * (1.0 / 3136.0);
    double vr = dS[576 + t] * (1.0 / 3136.0) - s * s;
    float scale = g1[t] * rsqrtf((float)vr + 1e-5f);
    ssc[t] = scale; ssb[t] = b1[t] - (float)s * scale;
  }
  __syncthreads();

  const float* src = T2b + (size_t)b * 64 * 960 + chunk * 224;
  float4* s4 = (float4*)sT;
  #pragma unroll
  for (int q = 0; q < 18; q++){
    int flat = q * 256 + t;                // 0..4607
    int c = flat / 72;
    int w = flat - c * 72;
    float4 v = *(const float4*)(src + (size_t)c * 960 + w * 4);
    int rr = w >> 3;                       // 0..8
    int prow = chunk * 7 + rr;             // padded row 0..29
    bool rok = (prow >= 1) && (prow <= 28);
    int pc0 = (w & 7) * 4;                 // padded col of v.x
    float sc = ssc[c], sb = ssb[c];
    v.x = (rok && pc0     >= 1 && pc0     <= 28) ? fmaxf(v.x * sc + sb, 0.f) : 0.f;
    v.y = (rok && pc0 + 1 >= 1 && pc0 + 1 <= 28) ? fmaxf(v.y * sc + sb, 0.f) : 0.f;
    v.z = (rok && pc0 + 2 >= 1 && pc0 + 2 <= 28) ? fmaxf(v.z * sc + sb, 0.f) : 0.f;
    v.w = (rok && pc0 + 3 >= 1 && pc0 + 3 <= 28) ? fmaxf(v.w * sc + sb, 0.f) : 0.f;
    s4[flat] = v;
  }
  __syncthreads();

  const float* __restrict__ wA = f_c2 + oc0 * 576;
  const float* __restrict__ wB = wA + 576;
  float v0 = 0.0f, v1 = 0.0f;
  if (t < 196){
    const int r = t / 28, col = t - r * 28;
    const float* pbase = sT + r * 32 + col;
    float c0 = 0.0f, c1 = 0.0f;
    #pragma unroll 4
    for (int c = 0; c < 64; c++){
      const float* p = pbase + c * 288;
      float t0 = p[0],  t1 = p[1],  t2 = p[2];
      float t3 = p[32], t4 = p[33], t5 = p[34];
      float t6 = p[64], t7 = p[65], t8 = p[66];
      const float* wa = wA + c * 9;
      const float* wb = wB + c * 9;
      c0 += fabsf(t0 - wa[0]) + fabsf(t1 - wa[1]) + fabsf(t2 - wa[2])
          + fabsf(t3 - wa[3]) + fabsf(t4 - wa[4]) + fabsf(t5 - wa[5])
          + fabsf(t6 - wa[6]) + fabsf(t7 - wa[7]) + fabsf(t8 - wa[8]);
      c1 += fabsf(t0 - wb[0]) + fabsf(t1 - wb[1]) + fabsf(t2 - wb[2])
          + fabsf(t3 - wb[3]) + fabsf(t4 - wb[4]) + fabsf(t5 - wb[5])
          + fabsf(t6 - wb[6]) + fabsf(t7 - wb[7]) + fabsf(t8 - wb[8]);
    }
    v0 = -c0; v1 = -c1;
    const int px = chunk * 196 + t;
    T3[((size_t)(b * 64 + oc0)) * HW + px]     = v0;
    T3[((size_t)(b * 64 + oc0 + 1)) * HW + px] = v1;
  }
  stats2(v0, v1, dS + 640, dS + 704, oc0);
}

// --------------- K3: adder 1x1 64->256 (bn2 inline, vectorized) ------------
// 512 blocks: chunk = a&1 (392 px), og = (a>>1)&63 (4 oc), b = a>>7.
// 2 px/thread (float2), float4 weight/scale reads from LDS.
__global__ __launch_bounds__(256) void back_kernel(
    const float* __restrict__ T3, const float* __restrict__ w_c3,
    const float* __restrict__ aff_c3, const float* __restrict__ mmbuf,
    const float* __restrict__ g2, const float* __restrict__ b2,
    float* __restrict__ out, double* __restrict__ dS)
{
  const int t = threadIdx.x;
  const int a = blockIdx.x;
  const int chunk = a & 1, og = (a >> 1) & 63, b = a >> 7;
  const int oc0 = og * 4;
  __shared__ __align__(16) float ssc[64];
  __shared__ __align__(16) float ssb[64];
  __shared__ __align__(16) float sw[256];
  __shared__ float saff[STAGE];
  if (t < 64){
    double s  = dS[640 + t] * (1.0 / 3136.0);
    double vr = dS[704 + t] * (1.0 / 3136.0) - s * s;
    float scale = g2[t] * rsqrtf((float)vr + 1e-5f);
    ssc[t] = scale; ssb[t] = b2[t] - (float)s * scale;
  }
  if (t >= 128 && t < 128 + STAGE) saff[t - 128] = aff_c3[t - 128];
  float mn, mx; mmReduce(mmbuf, 3, mn, mx);
  const float rng = mx - mn;
  __syncthreads();
  sw[t] = reconv(w_c3[oc0 * 64 + t], mn, rng, saff);
  __syncthreads();

  const int px0 = chunk * 392 + 2 * t;
  float a0x=0,a0y=0,a1x=0,a1y=0,a2x=0,a2y=0,a3x=0,a3y=0;
  if (t < 196){
    const float* bp = T3 + (size_t)b * 64 * HW + px0;
    #pragma unroll 4
    for (int c4 = 0; c4 < 16; c4++){
      const float4 sc = *(const float4*)&ssc[c4*4];
      const float4 sb = *(const float4*)&ssb[c4*4];
      const float4 w0 = *(const float4*)&sw[      c4*4];
      const float4 w1 = *(const float4*)&sw[ 64 + c4*4];
      const float4 w2 = *(const float4*)&sw[128 + c4*4];
      const float4 w3 = *(const float4*)&sw[192 + c4*4];
      const float2 x0 = *(const float2*)(bp + (size_t)(c4*4+0)*HW);
      const float2 x1 = *(const float2*)(bp + (size_t)(c4*4+1)*HW);
      const float2 x2 = *(const float2*)(bp + (size_t)(c4*4+2)*HW);
      const float2 x3 = *(const float2*)(bp + (size_t)(c4*4+3)*HW);
      float v0x = fmaxf(x0.x*sc.x+sb.x, 0.f), v0y = fmaxf(x0.y*sc.x+sb.x, 0.f);
      float v1x = fmaxf(x1.x*sc.y+sb.y, 0.f), v1y = fmaxf(x1.y*sc.y+sb.y, 0.f);
      float v2x = fmaxf(x2.x*sc.z+sb.z, 0.f), v2y = fmaxf(x2.y*sc.z+sb.z, 0.f);
      float v3x = fmaxf(x3.x*sc.w+sb.w, 0.f), v3y = fmaxf(x3.y*sc.w+sb.w, 0.f);
      a0x += fabsf(v0x-w0.x)+fabsf(v1x-w0.y)+fabsf(v2x-w0.z)+fabsf(v3x-w0.w);
      a0y += fabsf(v0y-w0.x)+fabsf(v1y-w0.y)+fabsf(v2y-w0.z)+fabsf(v3y-w0.w);
      a1x += fabsf(v0x-w1.x)+fabsf(v1x-w1.y)+fabsf(v2x-w1.z)+fabsf(v3x-w1.w);
      a1y += fabsf(v0y-w1.x)+fabsf(v1y-w1.y)+fabsf(v2y-w1.z)+fabsf(v3y-w1.w);
      a2x += fabsf(v0x-w2.x)+fabsf(v1x-w2.y)+fabsf(v2x-w2.z)+fabsf(v3x-w2.w);
      a2y += fabsf(v0y-w2.x)+fabsf(v1y-w2.y)+fabsf(v2y-w2.z)+fabsf(v3y-w2.w);
      a3x += fabsf(v0x-w3.x)+fabsf(v1x-w3.y)+fabsf(v2x-w3.z)+fabsf(v3x-w3.w);
      a3y += fabsf(v0y-w3.x)+fabsf(v1y-w3.y)+fabsf(v2y-w3.z)+fabsf(v3y-w3.w);
    }
    float* op = out + ((size_t)(b * 256 + oc0)) * HW + px0;
    float2 r;
    r.x = -a0x; r.y = -a0y; *(float2*)(op         ) = r;
    r.x = -a1x; r.y = -a1y; *(float2*)(op +     HW) = r;
    r.x = -a2x; r.y = -a2y; *(float2*)(op + 2 * HW) = r;
    r.x = -a3x; r.y = -a3y; *(float2*)(op + 3 * HW) = r;
  }
  {
    double s[4], q[4];
    s[0] = -(double)a0x - (double)a0y;
    s[1] = -(double)a1x - (double)a1y;
    s[2] = -(double)a2x - (double)a2y;
    s[3] = -(double)a3x - (double)a3y;
    q[0] = (double)a0x*a0x + (double)a0y*a0y;
    q[1] = (double)a1x*a1x + (double)a1y*a1y;
    q[2] = (double)a2x*a2x + (double)a2y*a2y;
    q[3] = (double)a3x*a3x + (double)a3y*a3y;
    stats4p(s, q, dS + 768, dS + 1024, oc0);
  }
}

// --------------- K4: bn3 + bnds finalize, residual, relu, kl (float4) ------
__global__ __launch_bounds__(256) void final_kernel(
    float* __restrict__ out, const float* __restrict__ A,
    const float* __restrict__ g3, const float* __restrict__ b3,
    const float* __restrict__ gds, const float* __restrict__ bds,
    const double* __restrict__ dS)
{
  __shared__ float s3c[256], s3b[256], sdc[256], sdb[256];
  const int t = threadIdx.x;
  {
    double s  = dS[768 + t] * (1.0 / 3136.0);
    double vr = dS[1024 + t] * (1.0 / 3136.0) - s * s;
    float scale = g3[t] * rsqrtf((float)vr + 1e-5f);
    s3c[t] = scale; s3b[t] = b3[t] - (float)s * scale;
    s  = dS[t] * (1.0 / 3136.0);
    vr = dS[256 + t] * (1.0 / 3136.0) - s * s;
    scale = gds[t] * rsqrtf((float)vr + 1e-5f);
    sdc[t] = scale; sdb[t] = bds[t] - (float)s * scale;
  }
  __syncthreads();
  {
    const int n4 = blockIdx.x * 256 + t;     // float4 index; 784%4==0 so
    const int c = (n4 / 196) & 255;          // all 4 elems share channel c
    float4 h  = *(const float4*)&out[(size_t)n4 * 4];
    float4 aa = *(const float4*)&A[(size_t)n4 * 4];
    const float scd = sdc[c], sbd = sdb[c], sc3 = s3c[c], sb3 = s3b[c];
    float4 o;
    o.x = fmaxf(h.x * sc3 + sb3 + fmaxf(aa.x * scd + sbd, 0.f), 0.f);
    o.y = fmaxf(h.y * sc3 + sb3 + fmaxf(aa.y * scd + sbd, 0.f), 0.f);
    o.z = fmaxf(h.z * sc3 + sb3 + fmaxf(aa.z * scd + sbd, 0.f), 0.f);
    o.w = fmaxf(h.w * sc3 + sb3 + fmaxf(aa.w * scd + sbd, 0.f), 0.f);
    *(float4*)&out[(size_t)n4 * 4] = o;
  }
  if (blockIdx.x == 0 && t == 0){
    const int ns[4] = {32768, 8192, 36864, 16384};
    float kl = 0.0f;
    #pragma unroll
    for (int q = 0; q < 4; q++){
      double se  = dS[1280 + q * 4];
      double sel = dS[1280 + q * 4 + 1];
      double sef = dS[1280 + q * 4 + 2];
      double sq  = dS[1280 + q * 4 + 3];
      kl += (float)((((sel - sef) / se) - log(se) + log(sq)) / (double)ns[q]);
    }
    out[802816] = kl;
  }
}

// ===========================================================================
extern "C" void kernel_launch(void* const* d_in, const int* in_sizes, int n_in,
                              void* d_out, int out_size, void* d_ws, size_t ws_size,
                              hipStream_t stream)
{
  const float* x      = (const float*)d_in[0];
  const float* sw_ds  = (const float*)d_in[1];
  const float* sw_c1  = (const float*)d_in[2];
  const float* sw_c2  = (const float*)d_in[3];
  const float* sw_c3  = (const float*)d_in[4];
  const float* a_ds   = (const float*)d_in[5];
  const float* a_c1   = (const float*)d_in[6];
  const float* a_c2   = (const float*)d_in[7];
  const float* a_c3   = (const float*)d_in[8];
  const float* peg_w  = (const float*)d_in[9];
  const float* bn1_g  = (const float*)d_in[10];
  const float* bn1_b  = (const float*)d_in[11];
  const float* bn2_g  = (const float*)d_in[12];
  const float* bn2_b  = (const float*)d_in[13];
  const float* bn3_g  = (const float*)d_in[14];
  const float* bn3_b  = (const float*)d_in[15];
  const float* bnds_g = (const float*)d_in[16];
  const float* bnds_b = (const float*)d_in[17];
  const float* lap_ds = (const float*)d_in[18];
  const float* lap_c1 = (const float*)d_in[19];
  const float* lap_c2 = (const float*)d_in[20];
  const float* lap_c3 = (const float*)d_in[21];

  float* ws    = (float*)d_ws;
  float* f_c2  = ws;                        // 36864
  float* mmbuf = ws + 36864;                // 128
  double* dstat= (double*)(ws + 37120);     // 1344 doubles -> 2688 floats
  float* A     = ws + 39808;                // 802816
  float* T3    = ws + 842624;               // 200704
  float* T2b   = ws + 1043328;              // 245760 (padded raw c1+PEG out)

  float* out = (float*)d_out;

  minmax_kernel<<<64, 256, 0, stream>>>(
      sw_ds, 32768, sw_c1, 8192, sw_c2, 36864, sw_c3, 16384, mmbuf, dstat);

  front_kernel<<<848, 256, 0, stream>>>(
      x, sw_ds, a_ds, lap_ds, sw_c1, a_c1, lap_c1,
      sw_c2, a_c2, lap_c2, f_c2, sw_c3, a_c3, lap_c3,
      peg_w, mmbuf, A, T2b, dstat);

  mid3x3_kernel<<<512, 256, 0, stream>>>(T2b, f_c2, bn1_g, bn1_b, T3, dstat);

  back_kernel<<<512, 256, 0, stream>>>(T3, sw_c3, a_c3, mmbuf,
                                       bn2_g, bn2_b, out, dstat);

  final_kernel<<<784, 256, 0, stream>>>(out, A, bn3_g, bn3_b, bnds_g, bnds_b,
                                        dstat);
}